// Round 13
// baseline (78.564 us; speedup 1.0000x reference)
//
#include <hip/hip_runtime.h>
#include <stdint.h>
#include <stddef.h>

// ---------------------------------------------------------------------------
// StructureAwareAttention  (B=2, L=1024, D=1024, H=16, HD=64)
//   prep: cvt x,sb -> bf16; transpose Wqkv/Ws/Wo -> [N][K] bf16   (1 kernel)
//   gemm01 (merged 128x128, BK=32, dbuf 1-barrier, 3 blocks/CU, T1 swizzle):
//       qkv -> q,k [B,H,L,64] bf16, v^T [B,H,64,L] bf16 ; sw -> bf16 [B,L,L]
//   attn: 8 waves split-KV, zero-transpose P, static-max softmax; XCD
//       co-location by (b,h) -> K/V (the bigger re-read) L2-resident
//   out = ctx@Wo + bo -> f32 (64x64 tile, 512 blocks = 2/CU, T1 swizzle)
// Workspace:
//   0: xb 4MB | 4MB: sbb 4MB | 8MB: Wqkv^T 6MB | 14MB: Ws^T 2MB | 16MB: Wo^T 2MB
//   18MB: q 4MB | 22MB: k 4MB | 26MB: v^T 4MB | 30MB: sw(bf16) 4MB | 38MB: ctx 4MB
// ---------------------------------------------------------------------------

typedef float f32x4 __attribute__((ext_vector_type(4)));
typedef short s16x8 __attribute__((ext_vector_type(8)));
typedef unsigned short u16x8 __attribute__((ext_vector_type(8)));
typedef unsigned short u16x4 __attribute__((ext_vector_type(4)));

__device__ inline unsigned short f2bf(float f) {          // RNE f32 -> bf16
    unsigned u = __builtin_bit_cast(unsigned, f);
    u += 0x7fffu + ((u >> 16) & 1u);
    return (unsigned short)(u >> 16);
}
__device__ inline float bf2f(unsigned short h) {
    return __builtin_bit_cast(float, (unsigned)h << 16);
}

__device__ inline f32x4 mfma16(s16x8 a, s16x8 b, f32x4 c) {
    return __builtin_amdgcn_mfma_f32_16x16x32_bf16(a, b, c, 0, 0, 0);
}

__device__ inline void gld_lds16(const void* g, const void* lds_base) {
    __builtin_amdgcn_global_load_lds(
        (const __attribute__((address_space(1))) void*)(uintptr_t)g,
        (__attribute__((address_space(3))) void*)(unsigned)(uintptr_t)lds_base,
        16, 0, 0);
}

// ------------------------------ prep ---------------------------------------
__global__ __launch_bounds__(256) void prep_k(const float* __restrict__ x,
                                              const float* __restrict__ sb,
                                              const float* __restrict__ Wqkv,
                                              const float* __restrict__ Ws,
                                              const float* __restrict__ Wo,
                                              unsigned short* __restrict__ xb,
                                              unsigned short* __restrict__ sbb,
                                              unsigned short* __restrict__ wqkvt,
                                              unsigned short* __restrict__ wst,
                                              unsigned short* __restrict__ wot) {
    __shared__ float tile[64][65];
    const int blk = blockIdx.x, t = threadIdx.x;
    if (blk < 2048) {
        const float* src = (blk < 1024) ? x : sb;
        unsigned short* dst = (blk < 1024) ? xb : sbb;
        int i = (blk & 1023) * 256 + t;
        const float4* s4 = (const float4*)src;
        float4 a = s4[2 * i], b = s4[2 * i + 1];
        u16x8 o;
        o[0] = f2bf(a.x); o[1] = f2bf(a.y); o[2] = f2bf(a.z); o[3] = f2bf(a.w);
        o[4] = f2bf(b.x); o[5] = f2bf(b.y); o[6] = f2bf(b.z); o[7] = f2bf(b.w);
        *(u16x8*)(dst + (size_t)i * 8) = o;
        return;
    }
    int tt = blk - 2048;
    const float* W; unsigned short* Wt; int N, n0, k0;
    if (tt < 768)       { W = Wqkv; Wt = wqkvt; N = 3072; n0 = (tt % 48) * 64; k0 = (tt / 48) * 64; }
    else if (tt < 1024) { tt -= 768;  W = Ws; Wt = wst; N = 1024; n0 = (tt & 15) * 64; k0 = (tt >> 4) * 64; }
    else                { tt -= 1024; W = Wo; Wt = wot; N = 1024; n0 = (tt & 15) * 64; k0 = (tt >> 4) * 64; }
    const int lr = t >> 4, lc = (t & 15) * 4;
#pragma unroll
    for (int rr = 0; rr < 4; rr++) {
        int r = lr + rr * 16;
        float4 v = *(const float4*)(W + (size_t)(k0 + r) * N + n0 + lc);
        tile[r][lc] = v.x; tile[r][lc + 1] = v.y; tile[r][lc + 2] = v.z; tile[r][lc + 3] = v.w;
    }
    __syncthreads();
    const int wn = t >> 3, wk = (t & 7) * 8;
#pragma unroll
    for (int rr = 0; rr < 2; rr++) {
        int n = wn + rr * 32;
        u16x8 o;
#pragma unroll
        for (int j = 0; j < 8; j++) o[j] = f2bf(tile[wk + j][n]);
        *(u16x8*)(Wt + (size_t)(n0 + n) * 1024 + k0 + wk) = o;
    }
}

// ---------------------- merged 128x128 GEMM (qkv + sw) ----------------------
// BK=32, dbuf (2x16KB LDS), 1 barrier/K-step, 3 blocks/CU (m97/m103 point).
// T1 XCD swizzle; sw output bf16. Rows are 4 16B-chunks; stage puts logical
// chunk (p ^ (row&3)) at phys p; reads XOR back -> conflict-light.
__global__ __launch_bounds__(256, 3) void gemm01_k(const unsigned short* __restrict__ xb,
                                                   const unsigned short* __restrict__ wqkvt,
                                                   const float* __restrict__ bqkv,
                                                   const unsigned short* __restrict__ sbb,
                                                   const unsigned short* __restrict__ wst,
                                                   const float* __restrict__ bs,
                                                   unsigned short* __restrict__ q,
                                                   unsigned short* __restrict__ kk_,
                                                   unsigned short* __restrict__ vt,
                                                   unsigned short* __restrict__ swb) {
    __shared__ unsigned short lA[2][4096];   // [128 m][32 k] per buf (8KB)
    __shared__ unsigned short lB[2][4096];   // [128 n][32 k] per buf
    const int id = blockIdx.x, t = threadIdx.x;
    const int blk = (id & 7) * 64 + (id >> 3);       // bijective (512 = 8*64)
    const int wave = t >> 6, lane = t & 63, c = lane & 15, g = lane >> 4;
    const int wr = (wave >> 1) * 64, wc = (wave & 1) * 64;

    const unsigned short* A;
    const unsigned short* Bt;
    const float* bias;
    int bn0, bm0, epi;
    if (blk < 384) { A = xb;  Bt = wqkvt; bias = bqkv; epi = 0;
                     bn0 = (blk % 24) * 128; bm0 = (blk / 24) * 128; }
    else           { int bb = blk - 384; A = sbb; Bt = wst; bias = bs; epi = 1;
                     bn0 = (bb & 7) * 128; bm0 = (bb >> 3) * 128; }

    // staging: 512 slots of 16B per matrix per buf; slot s: row=s>>2,
    // phys chunk s&3 holds logical chunk (s&3)^(row&3)
    size_t aoff[2], boff[2];
#pragma unroll
    for (int j = 0; j < 2; j++) {
        int s = j * 256 + t, row = s >> 2, ch = (s & 3) ^ (row & 3);
        aoff[j] = (size_t)(bm0 + row) * 1024 + ch * 8;
        boff[j] = (size_t)(bn0 + row) * 1024 + ch * 8;
    }
    char* lAb0 = (char*)lA[0]; char* lBb0 = (char*)lB[0];

#define GS32(buf, kt)                                                                     \
    do {                                                                                  \
        _Pragma("unroll")                                                                 \
        for (int j = 0; j < 2; j++)                                                       \
            gld_lds16(A + aoff[j] + (kt), lAb0 + (buf) * 8192 + j * 4096 + wave * 1024);  \
        _Pragma("unroll")                                                                 \
        for (int j = 0; j < 2; j++)                                                       \
            gld_lds16(Bt + boff[j] + (kt), lBb0 + (buf) * 8192 + j * 4096 + wave * 1024); \
    } while (0)

    f32x4 acc[4][4];
#pragma unroll
    for (int i = 0; i < 4; i++)
#pragma unroll
        for (int j = 0; j < 4; j++) acc[i][j] = {0.f, 0.f, 0.f, 0.f};

    GS32(0, 0);
    for (int ks = 0; ks < 32; ++ks) {
        __syncthreads();                              // stage of buf ks&1 landed
        if (ks < 31) GS32((ks + 1) & 1, (ks + 1) * 32);
        const char* aB = lAb0 + (ks & 1) * 8192;
        const char* bB = lBb0 + (ks & 1) * 8192;
        s16x8 af[4], bfr[4];
#pragma unroll
        for (int i = 0; i < 4; i++) {
            int r_ = wr + i * 16 + c;
            af[i] = *(const s16x8*)(aB + r_ * 64 + ((g ^ (r_ & 3)) << 4));
        }
#pragma unroll
        for (int j = 0; j < 4; j++) {
            int r_ = wc + j * 16 + c;
            bfr[j] = *(const s16x8*)(bB + r_ * 64 + ((g ^ (r_ & 3)) << 4));
        }
        __builtin_amdgcn_s_setprio(1);
#pragma unroll
        for (int i = 0; i < 4; i++)
#pragma unroll
            for (int j = 0; j < 4; j++)
                acc[i][j] = mfma16(af[i], bfr[j], acc[i][j]);
        __builtin_amdgcn_s_setprio(0);
    }
#undef GS32

#pragma unroll
    for (int i = 0; i < 4; i++) {
#pragma unroll
        for (int j = 0; j < 4; j++) {
            const int n = bn0 + wc + j * 16 + c;
            const float bv = bias[n];
#pragma unroll
            for (int r = 0; r < 4; r++) {
                const int m = bm0 + wr + i * 16 + g * 4 + r;
                float v = acc[i][j][r] + bv;
                if (epi == 0) {
                    const int sel = n >> 10, h = (n >> 6) & 15, d = n & 63;
                    const int b_ = m >> 10, l_ = m & 1023;
                    const size_t bh = (size_t)((b_ << 4) + h);
                    unsigned short hv = f2bf(v);
                    if (sel == 0)      q[(bh * 1024 + l_) * 64 + d] = hv;
                    else if (sel == 1) kk_[(bh * 1024 + l_) * 64 + d] = hv;
                    else               vt[(bh * 64 + d) * 1024 + l_] = hv;
                } else {
                    swb[(size_t)m * 1024 + n] = f2bf(v);
                }
            }
        }
    }
}

// ---------------------------- out GEMM (64x64) ------------------------------
__global__ __launch_bounds__(256, 2) void gemmo_k(const unsigned short* __restrict__ A,
                                                  const unsigned short* __restrict__ Bt,
                                                  const float* __restrict__ bias,
                                                  float* __restrict__ outf) {
    __shared__ unsigned short lA[2][4096];   // [64 m][64 k] per buf
    __shared__ unsigned short lB[2][4096];   // [64 n][64 k] per buf
    const int id = blockIdx.x, t = threadIdx.x;
    const int blk = (id & 7) * 64 + (id >> 3);       // bijective (512 = 8*64)
    const int wave = t >> 6, lane = t & 63, c = lane & 15, g = lane >> 4;
    const int bn0 = (blk & 15) * 64, bm0 = (blk >> 4) * 64;
    const int wr = (wave >> 1) * 32, wc = (wave & 1) * 32;

    size_t aoff[2], boff[2];
#pragma unroll
    for (int j = 0; j < 2; j++) {
        int s = j * 256 + t, row = s >> 3, ch = (s & 7) ^ (row & 7);
        aoff[j] = (size_t)(bm0 + row) * 1024 + ch * 8;
        boff[j] = (size_t)(bn0 + row) * 1024 + ch * 8;
    }
    char* lAb0 = (char*)lA[0]; char* lBb0 = (char*)lB[0];

#define GSTAGE(buf, kt)                                                                  \
    do {                                                                                 \
        _Pragma("unroll")                                                                \
        for (int j = 0; j < 2; j++)                                                      \
            gld_lds16(A + aoff[j] + (kt), lAb0 + (buf) * 8192 + j * 4096 + wave * 1024); \
        _Pragma("unroll")                                                                \
        for (int j = 0; j < 2; j++)                                                      \
            gld_lds16(Bt + boff[j] + (kt), lBb0 + (buf) * 8192 + j * 4096 + wave * 1024);\
    } while (0)

    f32x4 acc[2][2];
#pragma unroll
    for (int i = 0; i < 2; i++)
#pragma unroll
        for (int j = 0; j < 2; j++) acc[i][j] = {0.f, 0.f, 0.f, 0.f};

    GSTAGE(0, 0);
    for (int ks = 0; ks < 16; ++ks) {
        __syncthreads();
        if (ks < 15) GSTAGE((ks + 1) & 1, (ks + 1) * 64);
        const char* aB = lAb0 + (ks & 1) * 8192;
        const char* bB = lBb0 + (ks & 1) * 8192;
#pragma unroll
        for (int kk2 = 0; kk2 < 2; ++kk2) {
            s16x8 af[2], bfr[2];
#pragma unroll
            for (int i = 0; i < 2; i++) {
                int r_ = wr + i * 16 + c;
                af[i] = *(const s16x8*)(aB + r_ * 128 + (((kk2 * 4 + g) ^ (r_ & 7)) << 4));
            }
#pragma unroll
            for (int j = 0; j < 2; j++) {
                int r_ = wc + j * 16 + c;
                bfr[j] = *(const s16x8*)(bB + r_ * 128 + (((kk2 * 4 + g) ^ (r_ & 7)) << 4));
            }
            __builtin_amdgcn_s_setprio(1);
#pragma unroll
            for (int i = 0; i < 2; i++)
#pragma unroll
                for (int j = 0; j < 2; j++)
                    acc[i][j] = mfma16(af[i], bfr[j], acc[i][j]);
            __builtin_amdgcn_s_setprio(0);
        }
    }
#undef GSTAGE

#pragma unroll
    for (int i = 0; i < 2; i++) {
#pragma unroll
        for (int j = 0; j < 2; j++) {
            const int n = bn0 + wc + j * 16 + c;
            const float bv = bias[n];
#pragma unroll
            for (int r = 0; r < 4; r++) {
                const int m = bm0 + wr + i * 16 + g * 4 + r;
                outf[(size_t)m * 1024 + n] = acc[i][j][r] + bv;
            }
        }
    }
}

// ------------------------------ attention ----------------------------------
// XCD co-location by (b,h): the 16 qt-blocks sharing one head's K/V (256 KB,
// the LARGER re-read operand) land on the same XCD -> K/V L2-resident.
// Decode: pos=id>>3; bh=(id&7)*4+(pos>>4); qt=pos&15.
// Zero-transpose P + row-bit3 swizzle; static-max P=exp2(z-16) (sw bf16);
// l via ones-MFMA; split-KV groups merge by plain add.
__global__ __launch_bounds__(512, 4) void attn_k(const unsigned short* __restrict__ q,
                                                 const unsigned short* __restrict__ k,
                                                 const unsigned short* __restrict__ vt,
                                                 const unsigned short* __restrict__ sw,
                                                 unsigned short* __restrict__ ctx) {
    __shared__ unsigned short kbuf[2][2][4096];      // [group][buf][64kv x 64hd] 32KB
    __shared__ unsigned short vbuf[2][2][4096];      // [group][buf][64d x 64kv]  32KB
    const int t = threadIdx.x, wave = t >> 6, lane = t & 63, c = lane & 15, g = lane >> 4;
    const int grp = wave >> 2, wl = wave & 3;
    const int id = blockIdx.x;
    const int pos = id >> 3;
    const int bh = (id & 7) * 4 + (pos >> 4);        // (b,h) in [0,32) — co-located
    const int qt = pos & 15;
    const int b_ = bh >> 4, h = bh & 15;
    const int qr = qt * 64 + wl * 16;

    const unsigned short* qbase = q + ((size_t)bh * 1024 + qr) * 64;
    s16x8 qf0 = *(const s16x8*)(qbase + (size_t)c * 64 + g * 8);
    s16x8 qf1 = *(const s16x8*)(qbase + (size_t)c * 64 + 32 + g * 8);

    const unsigned short* kg  = k + (size_t)bh * 65536 + (size_t)grp * 512 * 64;  // rows kv
    const unsigned short* vgb = vt + (size_t)bh * 65536 + grp * 512;              // cols kv
    const unsigned short* swrow = sw + ((size_t)b_ * 1024 + qr + c) * 1024 + grp * 512;

    const int s0 = wl * 128 + lane, s1 = s0 + 64;
    const int r0 = s0 >> 3, ch0 = (s0 & 7) ^ (r0 & 7) ^ (((r0 >> 3) & 1) << 2);
    const int r1 = s1 >> 3, ch1 = (s1 & 7) ^ (r1 & 7) ^ (((r1 >> 3) & 1) << 2);

    const float SC  = 0.125f * 1.4426950408889634f;  // (1/sqrt(64)) * log2(e)
    const float L2E = 1.4426950408889634f;
    const float SHIFT = 16.0f;                       // static max (exp2 domain)

    const short one_bf = (short)0x3F80;              // bf16 1.0
    const s16x8 ones = { one_bf, one_bf, one_bf, one_bf, one_bf, one_bf, one_bf, one_bf };

    f32x4 acc[4];                    // acc[nf][r] = ctx^T[d = nf*16+4g+r][q = c]
    f32x4 accl = {0.f, 0.f, 0.f, 0.f};
#pragma unroll
    for (int nf = 0; nf < 4; nf++) acc[nf] = {0.f, 0.f, 0.f, 0.f};

    // permuted K-row base: A-row j=c holds K-row prm (mfma1) / prm+4 (mfma2)
    const int prm = ((c >> 2) << 3) | (c & 3);       // rows 8a+b
    const int sz0 = (c & 3) ^ (((c >> 2) & 1) << 2); // swz(prm)
    const int sz2 = sz0 ^ 4;                         // swz(prm+4)
    const int swzv = (c & 7) ^ (((c >> 3) & 1) << 2);// swz(nf*16+c)

    char* kgrp = (char*)kbuf + grp * 16384;
    char* vgrp = (char*)vbuf + grp * 16384;

#define STAGE(buf, kv0)                                                                     \
    do {                                                                                    \
        gld_lds16(kg + (size_t)((kv0) + r0) * 64 + ch0 * 8, kgrp + (buf) * 8192 + wl * 2048);          \
        gld_lds16(kg + (size_t)((kv0) + r1) * 64 + ch1 * 8, kgrp + (buf) * 8192 + wl * 2048 + 1024);   \
        gld_lds16(vgb + (size_t)r0 * 1024 + (kv0) + ch0 * 8, vgrp + (buf) * 8192 + wl * 2048);         \
        gld_lds16(vgb + (size_t)r1 * 1024 + (kv0) + ch1 * 8, vgrp + (buf) * 8192 + wl * 2048 + 1024);  \
    } while (0)

    STAGE(0, 0);
    __syncthreads();

    int cur = 0;
    for (int it = 0; it < 8; ++it) {
        const int kv0 = it * 64;
        if (it < 7) STAGE(cur ^ 1, kv0 + 64);

        const char* kB = kgrp + cur * 8192;
        const char* vB = vgrp + cur * 8192;
#pragma unroll
        for (int ks2 = 0; ks2 < 2; ++ks2) {
            // sw (bf16) for k = kv0 + ks2*32 + 8g .. +7 (one u16x8 = 16B)
            u16x8 swv = *(const u16x8*)(swrow + kv0 + ks2 * 32 + 8 * g);

            const int row0 = ks2 * 32 + prm;         // mfma1 rows (kv = 8g+r)
            const int row2 = row0 + 4;               // mfma2 rows (kv = 8g+4+r)
            s16x8 kc0 = *(const s16x8*)(kB + (row0 << 7) + (((0 + g) ^ sz0) << 4));
            s16x8 kc1 = *(const s16x8*)(kB + (row0 << 7) + (((4 + g) ^ sz0) << 4));
            s16x8 kc2 = *(const s16x8*)(kB + (row2 << 7) + (((0 + g) ^ sz2) << 4));
            s16x8 kc3 = *(const s16x8*)(kB + (row2 << 7) + (((4 + g) ^ sz2) << 4));

            __builtin_amdgcn_s_setprio(1);
            f32x4 ss0 = {0.f, 0.f, 0.f, 0.f}, ss1 = {0.f, 0.f, 0.f, 0.f};
            ss0 = mfma16(kc0, qf0, ss0); ss0 = mfma16(kc1, qf1, ss0);
            ss1 = mfma16(kc2, qf0, ss1); ss1 = mfma16(kc3, qf1, ss1);
            __builtin_amdgcn_s_setprio(0);

            // P = exp2(z - SHIFT); ss0[r] = S[k=8g+r], ss1[r] = S[k=8g+4+r]
            s16x8 ap;
#pragma unroll
            for (int r = 0; r < 4; r++) {
                float z0 = ss0[r] * SC + (bf2f(swv[r]) * L2E - SHIFT);
                float z1 = ss1[r] * SC + (bf2f(swv[4 + r]) * L2E - SHIFT);
                ap[r]     = (short)f2bf(__builtin_amdgcn_exp2f(z0));
                ap[4 + r] = (short)f2bf(__builtin_amdgcn_exp2f(z1));
            }

            __builtin_amdgcn_s_setprio(1);
            accl = mfma16(ones, ap, accl);               // l += row-sum of P
#pragma unroll
            for (int nf = 0; nf < 4; nf++) {
                s16x8 vf = *(const s16x8*)(vB + ((nf * 16 + c) << 7) + ((((ks2 << 2) + g) ^ swzv) << 4));
                acc[nf] = mfma16(vf, ap, acc[nf]);       // ctx^T += V^T . P^T
            }
            __builtin_amdgcn_s_setprio(0);
        }
        __syncthreads();
        cur ^= 1;
    }
#undef STAGE

    // ---- merge group 1 into group 0 (plain add: shared static shift) ----
    float* pscr = (float*)vbuf;                      // staging dead
    if (grp == 1) {
        float* pw = pscr + wl * 1040;                // 64d x 16q + 16 l
#pragma unroll
        for (int nf = 0; nf < 4; nf++)
#pragma unroll
            for (int r = 0; r < 4; r++)
                pw[(nf * 16 + 4 * g + r) * 16 + c] = acc[nf][r];
        if (g == 0) pw[1024 + c] = accl[0];
    }
    __syncthreads();

    float* scr = (float*)kbuf + wl * 1088;           // 64 x 17 transpose scratch
    if (grp == 0) {
        float* pw = pscr + wl * 1040;
#pragma unroll
        for (int nf = 0; nf < 4; nf++)
#pragma unroll
            for (int r = 0; r < 4; r++)
                acc[nf][r] += pw[(nf * 16 + 4 * g + r) * 16 + c];
        float inv = 1.0f / (accl[0] + pw[1024 + c]);
#pragma unroll
        for (int nf = 0; nf < 4; nf++)
#pragma unroll
            for (int r = 0; r < 4; r++)
                scr[(nf * 16 + 4 * g + r) * 17 + c] = acc[nf][r] * inv;
    }
    __syncthreads();
    if (grp == 0) {
        u16x8 o0, o1;
#pragma unroll
        for (int j = 0; j < 8; j++) o0[j] = f2bf(scr[(g * 16 + j) * 17 + c]);
#pragma unroll
        for (int j = 0; j < 8; j++) o1[j] = f2bf(scr[(g * 16 + 8 + j) * 17 + c]);
        unsigned short* dst = ctx + ((size_t)(b_ << 10) + qr + c) * 1024 + (h << 6) + g * 16;
        *(u16x8*)dst = o0;
        *(u16x8*)(dst + 8) = o1;
    }
}

// ------------------------------- launch ------------------------------------
extern "C" void kernel_launch(void* const* d_in, const int* in_sizes, int n_in,
                              void* d_out, int out_size, void* d_ws, size_t ws_size,
                              hipStream_t stream) {
    const float* x    = (const float*)d_in[0];
    const float* sb   = (const float*)d_in[1];
    const float* Wqkv = (const float*)d_in[2];
    const float* bqkv = (const float*)d_in[3];
    const float* Ws   = (const float*)d_in[4];
    const float* bs   = (const float*)d_in[5];
    const float* Wo   = (const float*)d_in[6];
    const float* bo   = (const float*)d_in[7];
    float* out = (float*)d_out;

    char* ws = (char*)d_ws;
    unsigned short* xb    = (unsigned short*)(ws);
    unsigned short* sbb   = (unsigned short*)(ws + ((size_t)4 << 20));
    unsigned short* wqkvt = (unsigned short*)(ws + ((size_t)8 << 20));
    unsigned short* wst   = (unsigned short*)(ws + ((size_t)14 << 20));
    unsigned short* wot   = (unsigned short*)(ws + ((size_t)16 << 20));
    unsigned short* qb    = (unsigned short*)(ws + ((size_t)18 << 20));
    unsigned short* kb    = (unsigned short*)(ws + ((size_t)22 << 20));
    unsigned short* vtb   = (unsigned short*)(ws + ((size_t)26 << 20));
    unsigned short* swbuf = (unsigned short*)(ws + ((size_t)30 << 20));
    unsigned short* ctxb  = (unsigned short*)(ws + ((size_t)38 << 20));

    prep_k<<<dim3(3328), dim3(256), 0, stream>>>(x, sb, Wqkv, Ws, Wo,
                                                 xb, sbb, wqkvt, wst, wot);
    gemm01_k<<<dim3(512), dim3(256), 0, stream>>>(xb, wqkvt, bqkv, sbb, wst, bs,
                                                  qb, kb, vtb, swbuf);
    attn_k<<<dim3(512), dim3(512), 0, stream>>>(qb, kb, vtb, swbuf, ctxb);
    gemmo_k<<<dim3(512), dim3(256), 0, stream>>>(ctxb, wot, bo, out);
}

// Round 14
// 75.852 us; speedup vs baseline: 1.0358x; 1.0358x over previous
//
#include <hip/hip_runtime.h>
#include <stdint.h>
#include <stddef.h>

// ---------------------------------------------------------------------------
// StructureAwareAttention  (B=2, L=1024, D=1024, H=16, HD=64)
//   prep: cvt x,sb -> bf16; transpose Wqkv/Ws/Wo -> [N][K] bf16   (1 kernel)
//   gemm01 (merged 128x128 BK=64 dbuf 2-phase, 512 blocks = 2/CU, T1 swizzle):
//       qkv -> q,k [B,H,L,64] bf16, v^T [B,H,64,L] bf16 ; sw -> bf16 [B,L,L]
//   attn: 8 waves split-KV, zero-transpose P, static-max softmax; XCD
//       co-location by (b,h) -> K/V (the bigger re-read) L2-resident
//   out = ctx@Wo + bo -> f32 (64x64 tile, 512 blocks = 2/CU, T1 swizzle)
// Workspace:
//   0: xb 4MB | 4MB: sbb 4MB | 8MB: Wqkv^T 6MB | 14MB: Ws^T 2MB | 16MB: Wo^T 2MB
//   18MB: q 4MB | 22MB: k 4MB | 26MB: v^T 4MB | 30MB: sw(bf16) 4MB | 38MB: ctx 4MB
// ---------------------------------------------------------------------------

typedef float f32x4 __attribute__((ext_vector_type(4)));
typedef short s16x8 __attribute__((ext_vector_type(8)));
typedef unsigned short u16x8 __attribute__((ext_vector_type(8)));
typedef unsigned short u16x4 __attribute__((ext_vector_type(4)));

__device__ inline unsigned short f2bf(float f) {          // RNE f32 -> bf16
    unsigned u = __builtin_bit_cast(unsigned, f);
    u += 0x7fffu + ((u >> 16) & 1u);
    return (unsigned short)(u >> 16);
}
__device__ inline float bf2f(unsigned short h) {
    return __builtin_bit_cast(float, (unsigned)h << 16);
}

__device__ inline f32x4 mfma16(s16x8 a, s16x8 b, f32x4 c) {
    return __builtin_amdgcn_mfma_f32_16x16x32_bf16(a, b, c, 0, 0, 0);
}

__device__ inline void gld_lds16(const void* g, const void* lds_base) {
    __builtin_amdgcn_global_load_lds(
        (const __attribute__((address_space(1))) void*)(uintptr_t)g,
        (__attribute__((address_space(3))) void*)(unsigned)(uintptr_t)lds_base,
        16, 0, 0);
}

// ------------------------------ prep ---------------------------------------
__global__ __launch_bounds__(256) void prep_k(const float* __restrict__ x,
                                              const float* __restrict__ sb,
                                              const float* __restrict__ Wqkv,
                                              const float* __restrict__ Ws,
                                              const float* __restrict__ Wo,
                                              unsigned short* __restrict__ xb,
                                              unsigned short* __restrict__ sbb,
                                              unsigned short* __restrict__ wqkvt,
                                              unsigned short* __restrict__ wst,
                                              unsigned short* __restrict__ wot) {
    __shared__ float tile[64][65];
    const int blk = blockIdx.x, t = threadIdx.x;
    if (blk < 2048) {
        const float* src = (blk < 1024) ? x : sb;
        unsigned short* dst = (blk < 1024) ? xb : sbb;
        int i = (blk & 1023) * 256 + t;
        const float4* s4 = (const float4*)src;
        float4 a = s4[2 * i], b = s4[2 * i + 1];
        u16x8 o;
        o[0] = f2bf(a.x); o[1] = f2bf(a.y); o[2] = f2bf(a.z); o[3] = f2bf(a.w);
        o[4] = f2bf(b.x); o[5] = f2bf(b.y); o[6] = f2bf(b.z); o[7] = f2bf(b.w);
        *(u16x8*)(dst + (size_t)i * 8) = o;
        return;
    }
    int tt = blk - 2048;
    const float* W; unsigned short* Wt; int N, n0, k0;
    if (tt < 768)       { W = Wqkv; Wt = wqkvt; N = 3072; n0 = (tt % 48) * 64; k0 = (tt / 48) * 64; }
    else if (tt < 1024) { tt -= 768;  W = Ws; Wt = wst; N = 1024; n0 = (tt & 15) * 64; k0 = (tt >> 4) * 64; }
    else                { tt -= 1024; W = Wo; Wt = wot; N = 1024; n0 = (tt & 15) * 64; k0 = (tt >> 4) * 64; }
    const int lr = t >> 4, lc = (t & 15) * 4;
#pragma unroll
    for (int rr = 0; rr < 4; rr++) {
        int r = lr + rr * 16;
        float4 v = *(const float4*)(W + (size_t)(k0 + r) * N + n0 + lc);
        tile[r][lc] = v.x; tile[r][lc + 1] = v.y; tile[r][lc + 2] = v.z; tile[r][lc + 3] = v.w;
    }
    __syncthreads();
    const int wn = t >> 3, wk = (t & 7) * 8;
#pragma unroll
    for (int rr = 0; rr < 2; rr++) {
        int n = wn + rr * 32;
        u16x8 o;
#pragma unroll
        for (int j = 0; j < 8; j++) o[j] = f2bf(tile[wk + j][n]);
        *(u16x8*)(Wt + (size_t)(n0 + n) * 1024 + k0 + wk) = o;
    }
}

// ---------------------- merged 128x128 GEMM (qkv + sw) ----------------------
// R12 version: BK=64, dbuf 2-phase (2x16KB+2x16KB LDS), 1 barrier/K-step,
// 2 blocks/CU. T1 XCD swizzle; sw output bf16.
__global__ __launch_bounds__(256, 2) void gemm01_k(const unsigned short* __restrict__ xb,
                                                   const unsigned short* __restrict__ wqkvt,
                                                   const float* __restrict__ bqkv,
                                                   const unsigned short* __restrict__ sbb,
                                                   const unsigned short* __restrict__ wst,
                                                   const float* __restrict__ bs,
                                                   unsigned short* __restrict__ q,
                                                   unsigned short* __restrict__ kk_,
                                                   unsigned short* __restrict__ vt,
                                                   unsigned short* __restrict__ swb) {
    __shared__ unsigned short lA[2][8192];   // [128 m][64 k] per buf
    __shared__ unsigned short lB[2][8192];   // [128 n][64 k] per buf
    const int id = blockIdx.x, t = threadIdx.x;
    const int blk = (id & 7) * 64 + (id >> 3);       // bijective (512 = 8*64)
    const int wave = t >> 6, lane = t & 63, c = lane & 15, g = lane >> 4;
    const int wr = (wave >> 1) * 64, wc = (wave & 1) * 64;

    const unsigned short* A;
    const unsigned short* Bt;
    const float* bias;
    int bn0, bm0, epi;
    if (blk < 384) { A = xb;  Bt = wqkvt; bias = bqkv; epi = 0;
                     bn0 = (blk % 24) * 128; bm0 = (blk / 24) * 128; }
    else           { int bb = blk - 384; A = sbb; Bt = wst; bias = bs; epi = 1;
                     bn0 = (bb & 7) * 128; bm0 = (bb >> 3) * 128; }

    size_t aoff[4], boff[4];
#pragma unroll
    for (int j = 0; j < 4; j++) {
        int s = j * 256 + t, row = s >> 3, ch = (s & 7) ^ (row & 7);
        aoff[j] = (size_t)(bm0 + row) * 1024 + ch * 8;
        boff[j] = (size_t)(bn0 + row) * 1024 + ch * 8;
    }
    char* lAb0 = (char*)lA[0]; char* lBb0 = (char*)lB[0];

#define GS128(buf, kt)                                                                    \
    do {                                                                                  \
        _Pragma("unroll")                                                                 \
        for (int j = 0; j < 4; j++)                                                       \
            gld_lds16(A + aoff[j] + (kt), lAb0 + (buf) * 16384 + j * 4096 + wave * 1024); \
        _Pragma("unroll")                                                                 \
        for (int j = 0; j < 4; j++)                                                       \
            gld_lds16(Bt + boff[j] + (kt), lBb0 + (buf) * 16384 + j * 4096 + wave * 1024);\
    } while (0)

    f32x4 acc[4][4];
#pragma unroll
    for (int i = 0; i < 4; i++)
#pragma unroll
        for (int j = 0; j < 4; j++) acc[i][j] = {0.f, 0.f, 0.f, 0.f};

    GS128(0, 0);
    for (int ks = 0; ks < 16; ++ks) {
        __syncthreads();
        if (ks < 15) GS128((ks + 1) & 1, (ks + 1) * 64);
        const char* aB = lAb0 + (ks & 1) * 16384;
        const char* bB = lBb0 + (ks & 1) * 16384;
#pragma unroll
        for (int kk2 = 0; kk2 < 2; ++kk2) {
            s16x8 af[4], bfr[4];
#pragma unroll
            for (int i = 0; i < 4; i++) {
                int r_ = wr + i * 16 + c;
                af[i] = *(const s16x8*)(aB + r_ * 128 + (((kk2 * 4 + g) ^ (r_ & 7)) << 4));
            }
#pragma unroll
            for (int j = 0; j < 4; j++) {
                int r_ = wc + j * 16 + c;
                bfr[j] = *(const s16x8*)(bB + r_ * 128 + (((kk2 * 4 + g) ^ (r_ & 7)) << 4));
            }
            __builtin_amdgcn_s_setprio(1);
#pragma unroll
            for (int i = 0; i < 4; i++)
#pragma unroll
                for (int j = 0; j < 4; j++)
                    acc[i][j] = mfma16(af[i], bfr[j], acc[i][j]);
            __builtin_amdgcn_s_setprio(0);
        }
    }
#undef GS128

#pragma unroll
    for (int i = 0; i < 4; i++) {
#pragma unroll
        for (int j = 0; j < 4; j++) {
            const int n = bn0 + wc + j * 16 + c;
            const float bv = bias[n];
#pragma unroll
            for (int r = 0; r < 4; r++) {
                const int m = bm0 + wr + i * 16 + g * 4 + r;
                float v = acc[i][j][r] + bv;
                if (epi == 0) {
                    const int sel = n >> 10, h = (n >> 6) & 15, d = n & 63;
                    const int b_ = m >> 10, l_ = m & 1023;
                    const size_t bh = (size_t)((b_ << 4) + h);
                    unsigned short hv = f2bf(v);
                    if (sel == 0)      q[(bh * 1024 + l_) * 64 + d] = hv;
                    else if (sel == 1) kk_[(bh * 1024 + l_) * 64 + d] = hv;
                    else               vt[(bh * 64 + d) * 1024 + l_] = hv;
                } else {
                    swb[(size_t)m * 1024 + n] = f2bf(v);
                }
            }
        }
    }
}

// ---------------------------- out GEMM (64x64) ------------------------------
__global__ __launch_bounds__(256, 2) void gemmo_k(const unsigned short* __restrict__ A,
                                                  const unsigned short* __restrict__ Bt,
                                                  const float* __restrict__ bias,
                                                  float* __restrict__ outf) {
    __shared__ unsigned short lA[2][4096];   // [64 m][64 k] per buf
    __shared__ unsigned short lB[2][4096];   // [64 n][64 k] per buf
    const int id = blockIdx.x, t = threadIdx.x;
    const int blk = (id & 7) * 64 + (id >> 3);       // bijective (512 = 8*64)
    const int wave = t >> 6, lane = t & 63, c = lane & 15, g = lane >> 4;
    const int bn0 = (blk & 15) * 64, bm0 = (blk >> 4) * 64;
    const int wr = (wave >> 1) * 32, wc = (wave & 1) * 32;

    size_t aoff[2], boff[2];
#pragma unroll
    for (int j = 0; j < 2; j++) {
        int s = j * 256 + t, row = s >> 3, ch = (s & 7) ^ (row & 7);
        aoff[j] = (size_t)(bm0 + row) * 1024 + ch * 8;
        boff[j] = (size_t)(bn0 + row) * 1024 + ch * 8;
    }
    char* lAb0 = (char*)lA[0]; char* lBb0 = (char*)lB[0];

#define GSTAGE(buf, kt)                                                                  \
    do {                                                                                 \
        _Pragma("unroll")                                                                \
        for (int j = 0; j < 2; j++)                                                      \
            gld_lds16(A + aoff[j] + (kt), lAb0 + (buf) * 8192 + j * 4096 + wave * 1024); \
        _Pragma("unroll")                                                                \
        for (int j = 0; j < 2; j++)                                                      \
            gld_lds16(Bt + boff[j] + (kt), lBb0 + (buf) * 8192 + j * 4096 + wave * 1024);\
    } while (0)

    f32x4 acc[2][2];
#pragma unroll
    for (int i = 0; i < 2; i++)
#pragma unroll
        for (int j = 0; j < 2; j++) acc[i][j] = {0.f, 0.f, 0.f, 0.f};

    GSTAGE(0, 0);
    for (int ks = 0; ks < 16; ++ks) {
        __syncthreads();
        if (ks < 15) GSTAGE((ks + 1) & 1, (ks + 1) * 64);
        const char* aB = lAb0 + (ks & 1) * 8192;
        const char* bB = lBb0 + (ks & 1) * 8192;
#pragma unroll
        for (int kk2 = 0; kk2 < 2; ++kk2) {
            s16x8 af[2], bfr[2];
#pragma unroll
            for (int i = 0; i < 2; i++) {
                int r_ = wr + i * 16 + c;
                af[i] = *(const s16x8*)(aB + r_ * 128 + (((kk2 * 4 + g) ^ (r_ & 7)) << 4));
            }
#pragma unroll
            for (int j = 0; j < 2; j++) {
                int r_ = wc + j * 16 + c;
                bfr[j] = *(const s16x8*)(bB + r_ * 128 + (((kk2 * 4 + g) ^ (r_ & 7)) << 4));
            }
            __builtin_amdgcn_s_setprio(1);
#pragma unroll
            for (int i = 0; i < 2; i++)
#pragma unroll
                for (int j = 0; j < 2; j++)
                    acc[i][j] = mfma16(af[i], bfr[j], acc[i][j]);
            __builtin_amdgcn_s_setprio(0);
        }
    }
#undef GSTAGE

#pragma unroll
    for (int i = 0; i < 2; i++) {
#pragma unroll
        for (int j = 0; j < 2; j++) {
            const int n = bn0 + wc + j * 16 + c;
            const float bv = bias[n];
#pragma unroll
            for (int r = 0; r < 4; r++) {
                const int m = bm0 + wr + i * 16 + g * 4 + r;
                outf[(size_t)m * 1024 + n] = acc[i][j][r] + bv;
            }
        }
    }
}

// ------------------------------ attention ----------------------------------
// XCD co-location by (b,h): the 16 qt-blocks sharing one head's K/V (256 KB,
// the LARGER re-read operand) land on the same XCD -> K/V L2-resident.
// Decode: pos=id>>3; bh=(id&7)*4+(pos>>4); qt=pos&15.
// Zero-transpose P + row-bit3 swizzle; static-max P=exp2(z-16) (sw bf16);
// l via ones-MFMA; split-KV groups merge by plain add.
__global__ __launch_bounds__(512, 4) void attn_k(const unsigned short* __restrict__ q,
                                                 const unsigned short* __restrict__ k,
                                                 const unsigned short* __restrict__ vt,
                                                 const unsigned short* __restrict__ sw,
                                                 unsigned short* __restrict__ ctx) {
    __shared__ unsigned short kbuf[2][2][4096];      // [group][buf][64kv x 64hd] 32KB
    __shared__ unsigned short vbuf[2][2][4096];      // [group][buf][64d x 64kv]  32KB
    const int t = threadIdx.x, wave = t >> 6, lane = t & 63, c = lane & 15, g = lane >> 4;
    const int grp = wave >> 2, wl = wave & 3;
    const int id = blockIdx.x;
    const int pos = id >> 3;
    const int bh = (id & 7) * 4 + (pos >> 4);        // (b,h) in [0,32) — co-located
    const int qt = pos & 15;
    const int b_ = bh >> 4, h = bh & 15;
    const int qr = qt * 64 + wl * 16;

    const unsigned short* qbase = q + ((size_t)bh * 1024 + qr) * 64;
    s16x8 qf0 = *(const s16x8*)(qbase + (size_t)c * 64 + g * 8);
    s16x8 qf1 = *(const s16x8*)(qbase + (size_t)c * 64 + 32 + g * 8);

    const unsigned short* kg  = k + (size_t)bh * 65536 + (size_t)grp * 512 * 64;  // rows kv
    const unsigned short* vgb = vt + (size_t)bh * 65536 + grp * 512;              // cols kv
    const unsigned short* swrow = sw + ((size_t)b_ * 1024 + qr + c) * 1024 + grp * 512;

    const int s0 = wl * 128 + lane, s1 = s0 + 64;
    const int r0 = s0 >> 3, ch0 = (s0 & 7) ^ (r0 & 7) ^ (((r0 >> 3) & 1) << 2);
    const int r1 = s1 >> 3, ch1 = (s1 & 7) ^ (r1 & 7) ^ (((r1 >> 3) & 1) << 2);

    const float SC  = 0.125f * 1.4426950408889634f;  // (1/sqrt(64)) * log2(e)
    const float L2E = 1.4426950408889634f;
    const float SHIFT = 16.0f;                       // static max (exp2 domain)

    const short one_bf = (short)0x3F80;              // bf16 1.0
    const s16x8 ones = { one_bf, one_bf, one_bf, one_bf, one_bf, one_bf, one_bf, one_bf };

    f32x4 acc[4];                    // acc[nf][r] = ctx^T[d = nf*16+4g+r][q = c]
    f32x4 accl = {0.f, 0.f, 0.f, 0.f};
#pragma unroll
    for (int nf = 0; nf < 4; nf++) acc[nf] = {0.f, 0.f, 0.f, 0.f};

    // permuted K-row base: A-row j=c holds K-row prm (mfma1) / prm+4 (mfma2)
    const int prm = ((c >> 2) << 3) | (c & 3);       // rows 8a+b
    const int sz0 = (c & 3) ^ (((c >> 2) & 1) << 2); // swz(prm)
    const int sz2 = sz0 ^ 4;                         // swz(prm+4)
    const int swzv = (c & 7) ^ (((c >> 3) & 1) << 2);// swz(nf*16+c)

    char* kgrp = (char*)kbuf + grp * 16384;
    char* vgrp = (char*)vbuf + grp * 16384;

#define STAGE(buf, kv0)                                                                     \
    do {                                                                                    \
        gld_lds16(kg + (size_t)((kv0) + r0) * 64 + ch0 * 8, kgrp + (buf) * 8192 + wl * 2048);          \
        gld_lds16(kg + (size_t)((kv0) + r1) * 64 + ch1 * 8, kgrp + (buf) * 8192 + wl * 2048 + 1024);   \
        gld_lds16(vgb + (size_t)r0 * 1024 + (kv0) + ch0 * 8, vgrp + (buf) * 8192 + wl * 2048);         \
        gld_lds16(vgb + (size_t)r1 * 1024 + (kv0) + ch1 * 8, vgrp + (buf) * 8192 + wl * 2048 + 1024);  \
    } while (0)

    STAGE(0, 0);
    __syncthreads();

    int cur = 0;
    for (int it = 0; it < 8; ++it) {
        const int kv0 = it * 64;
        if (it < 7) STAGE(cur ^ 1, kv0 + 64);

        const char* kB = kgrp + cur * 8192;
        const char* vB = vgrp + cur * 8192;
#pragma unroll
        for (int ks2 = 0; ks2 < 2; ++ks2) {
            // sw (bf16) for k = kv0 + ks2*32 + 8g .. +7 (one u16x8 = 16B)
            u16x8 swv = *(const u16x8*)(swrow + kv0 + ks2 * 32 + 8 * g);

            const int row0 = ks2 * 32 + prm;         // mfma1 rows (kv = 8g+r)
            const int row2 = row0 + 4;               // mfma2 rows (kv = 8g+4+r)
            s16x8 kc0 = *(const s16x8*)(kB + (row0 << 7) + (((0 + g) ^ sz0) << 4));
            s16x8 kc1 = *(const s16x8*)(kB + (row0 << 7) + (((4 + g) ^ sz0) << 4));
            s16x8 kc2 = *(const s16x8*)(kB + (row2 << 7) + (((0 + g) ^ sz2) << 4));
            s16x8 kc3 = *(const s16x8*)(kB + (row2 << 7) + (((4 + g) ^ sz2) << 4));

            __builtin_amdgcn_s_setprio(1);
            f32x4 ss0 = {0.f, 0.f, 0.f, 0.f}, ss1 = {0.f, 0.f, 0.f, 0.f};
            ss0 = mfma16(kc0, qf0, ss0); ss0 = mfma16(kc1, qf1, ss0);
            ss1 = mfma16(kc2, qf0, ss1); ss1 = mfma16(kc3, qf1, ss1);
            __builtin_amdgcn_s_setprio(0);

            // P = exp2(z - SHIFT); ss0[r] = S[k=8g+r], ss1[r] = S[k=8g+4+r]
            s16x8 ap;
#pragma unroll
            for (int r = 0; r < 4; r++) {
                float z0 = ss0[r] * SC + (bf2f(swv[r]) * L2E - SHIFT);
                float z1 = ss1[r] * SC + (bf2f(swv[4 + r]) * L2E - SHIFT);
                ap[r]     = (short)f2bf(__builtin_amdgcn_exp2f(z0));
                ap[4 + r] = (short)f2bf(__builtin_amdgcn_exp2f(z1));
            }

            __builtin_amdgcn_s_setprio(1);
            accl = mfma16(ones, ap, accl);               // l += row-sum of P
#pragma unroll
            for (int nf = 0; nf < 4; nf++) {
                s16x8 vf = *(const s16x8*)(vB + ((nf * 16 + c) << 7) + ((((ks2 << 2) + g) ^ swzv) << 4));
                acc[nf] = mfma16(vf, ap, acc[nf]);       // ctx^T += V^T . P^T
            }
            __builtin_amdgcn_s_setprio(0);
        }
        __syncthreads();
        cur ^= 1;
    }
#undef STAGE

    // ---- merge group 1 into group 0 (plain add: shared static shift) ----
    float* pscr = (float*)vbuf;                      // staging dead
    if (grp == 1) {
        float* pw = pscr + wl * 1040;                // 64d x 16q + 16 l
#pragma unroll
        for (int nf = 0; nf < 4; nf++)
#pragma unroll
            for (int r = 0; r < 4; r++)
                pw[(nf * 16 + 4 * g + r) * 16 + c] = acc[nf][r];
        if (g == 0) pw[1024 + c] = accl[0];
    }
    __syncthreads();

    float* scr = (float*)kbuf + wl * 1088;           // 64 x 17 transpose scratch
    if (grp == 0) {
        float* pw = pscr + wl * 1040;
#pragma unroll
        for (int nf = 0; nf < 4; nf++)
#pragma unroll
            for (int r = 0; r < 4; r++)
                acc[nf][r] += pw[(nf * 16 + 4 * g + r) * 16 + c];
        float inv = 1.0f / (accl[0] + pw[1024 + c]);
#pragma unroll
        for (int nf = 0; nf < 4; nf++)
#pragma unroll
            for (int r = 0; r < 4; r++)
                scr[(nf * 16 + 4 * g + r) * 17 + c] = acc[nf][r] * inv;
    }
    __syncthreads();
    if (grp == 0) {
        u16x8 o0, o1;
#pragma unroll
        for (int j = 0; j < 8; j++) o0[j] = f2bf(scr[(g * 16 + j) * 17 + c]);
#pragma unroll
        for (int j = 0; j < 8; j++) o1[j] = f2bf(scr[(g * 16 + 8 + j) * 17 + c]);
        unsigned short* dst = ctx + ((size_t)(b_ << 10) + qr + c) * 1024 + (h << 6) + g * 16;
        *(u16x8*)dst = o0;
        *(u16x8*)(dst + 8) = o1;
    }
}

// ------------------------------- launch ------------------------------------
extern "C" void kernel_launch(void* const* d_in, const int* in_sizes, int n_in,
                              void* d_out, int out_size, void* d_ws, size_t ws_size,
                              hipStream_t stream) {
    const float* x    = (const float*)d_in[0];
    const float* sb   = (const float*)d_in[1];
    const float* Wqkv = (const float*)d_in[2];
    const float* bqkv = (const float*)d_in[3];
    const float* Ws   = (const float*)d_in[4];
    const float* bs   = (const float*)d_in[5];
    const float* Wo   = (const float*)d_in[6];
    const float* bo   = (const float*)d_in[7];
    float* out = (float*)d_out;

    char* ws = (char*)d_ws;
    unsigned short* xb    = (unsigned short*)(ws);
    unsigned short* sbb   = (unsigned short*)(ws + ((size_t)4 << 20));
    unsigned short* wqkvt = (unsigned short*)(ws + ((size_t)8 << 20));
    unsigned short* wst   = (unsigned short*)(ws + ((size_t)14 << 20));
    unsigned short* wot   = (unsigned short*)(ws + ((size_t)16 << 20));
    unsigned short* qb    = (unsigned short*)(ws + ((size_t)18 << 20));
    unsigned short* kb    = (unsigned short*)(ws + ((size_t)22 << 20));
    unsigned short* vtb   = (unsigned short*)(ws + ((size_t)26 << 20));
    unsigned short* swbuf = (unsigned short*)(ws + ((size_t)30 << 20));
    unsigned short* ctxb  = (unsigned short*)(ws + ((size_t)38 << 20));

    prep_k<<<dim3(3328), dim3(256), 0, stream>>>(x, sb, Wqkv, Ws, Wo,
                                                 xb, sbb, wqkvt, wst, wot);
    gemm01_k<<<dim3(512), dim3(256), 0, stream>>>(xb, wqkvt, bqkv, sbb, wst, bs,
                                                  qb, kb, vtb, swbuf);
    attn_k<<<dim3(512), dim3(512), 0, stream>>>(qb, kb, vtb, swbuf, ctxb);
    gemmo_k<<<dim3(512), dim3(256), 0, stream>>>(ctxb, wot, bo, out);
}